// Round 1
// baseline (958.492 us; speedup 1.0000x reference)
//
#include <hip/hip_runtime.h>
#include <hip/hip_bf16.h>
#include <cstdint>

#define T_TOK 2048
#define HID   2048
#define NEXP  64
#define TOPK  6
#define NLOC  8
#define ITR   1408
#define ITR2  2816
#define NSLOT (T_TOK * TOPK)   // 12288 upper bound on (token, local expert) pairs

// workspace layout (bytes)
#define OFF_CNT   0
#define OFF_CNT2  32
#define OFF_OFFS  64
#define OFF_TOPID 4096
#define OFF_TOPW  (OFF_TOPID + T_TOK * TOPK * 4)   // 53248
#define OFF_TOK   (OFF_TOPW  + T_TOK * TOPK * 4)   // 102400
#define OFF_WOF   (OFF_TOK   + NSLOT * 4)          // 151552
#define OFF_ABUF  (OFF_WOF   + NSLOT * 4)          // 200704 (256-aligned)

#define KC 16

// ---------------- routing: softmax + top-6 (stable tie-break) ----------------
__global__ __launch_bounds__(256) void k_route(
    const float* __restrict__ logits, int* __restrict__ cnt,
    int* __restrict__ top_ids, float* __restrict__ top_w)
{
    const int lane = threadIdx.x & 63;
    const int t = blockIdx.x * 4 + (threadIdx.x >> 6);

    float v = logits[t * NEXP + lane];
    float m = v;
    #pragma unroll
    for (int s = 32; s > 0; s >>= 1) m = fmaxf(m, __shfl_xor(m, s));
    float ev = expf(v - m);
    float ssum = ev;
    #pragma unroll
    for (int s = 32; s > 0; s >>= 1) ssum += __shfl_xor(ssum, s);
    float p = ev / ssum;

    float pv = p;
    int ids[TOPK]; float wsel[TOPK]; float wsum = 0.f;
    #pragma unroll
    for (int i = 0; i < TOPK; ++i) {
        float mx = pv;
        #pragma unroll
        for (int s = 32; s > 0; s >>= 1) mx = fmaxf(mx, __shfl_xor(mx, s));
        unsigned long long b = __ballot(pv == mx);
        int idx = (int)__builtin_ctzll(b);     // lowest index on ties == lax.top_k
        float w = __shfl(p, idx);
        ids[i] = idx; wsel[i] = w; wsum += w;
        if (lane == idx) pv = -1.0f;
    }
    if (lane < TOPK) {
        top_ids[t * TOPK + lane] = ids[lane];
        top_w[t * TOPK + lane]  = wsel[lane] / wsum;
    }
    if (lane == 0) {
        #pragma unroll
        for (int i = 0; i < TOPK; ++i)
            if ((ids[i] & 7) == 0) atomicAdd(&cnt[ids[i] >> 3], 1);
    }
}

__global__ void k_offsets(int* __restrict__ cnt, int* __restrict__ cnt2,
                          int* __restrict__ offs)
{
    if (threadIdx.x == 0) {
        int s = 0;
        for (int e = 0; e < NLOC; ++e) { offs[e] = s; s += cnt[e]; cnt2[e] = 0; }
    }
}

__global__ __launch_bounds__(256) void k_scatter(
    const int* __restrict__ top_ids, const float* __restrict__ top_w,
    const int* __restrict__ offs, int* __restrict__ cnt2,
    int* __restrict__ tok_of, float* __restrict__ w_of)
{
    const int t = blockIdx.x * 256 + threadIdx.x;
    #pragma unroll
    for (int i = 0; i < TOPK; ++i) {
        int id = top_ids[t * TOPK + i];
        if ((id & 7) == 0) {
            int e = id >> 3;
            int s = offs[e] + atomicAdd(&cnt2[e], 1);
            tok_of[s] = t;
            w_of[s]  = top_w[t * TOPK + i];
        }
    }
}

// ------------- GEMM1: a = silu(x @ w13g^T * sg) * (x @ w13u^T * su) -------------
// tile: 64 tokens x 128 inter-columns (gate+up pair), fp32 FMA, scale folded at staging
__global__ __launch_bounds__(256) void k_gemm1(
    const float* __restrict__ x, const float* __restrict__ w13,
    const float* __restrict__ w13s, const int* __restrict__ offs,
    const int* __restrict__ cnt, const int* __restrict__ tok_of,
    float* __restrict__ a_buf)
{
    const int e = blockIdx.z;
    const int cntE = cnt[e];
    const int m0 = blockIdx.y * 64;
    if (m0 >= cntE) return;
    const int n0 = blockIdx.x * 128;
    const int base = offs[e] + m0;
    const int tid = threadIdx.x;

    __shared__ float xs[KC][68];
    __shared__ float wgs[KC][132];
    __shared__ float wus[KC][132];
    __shared__ int   toks[64];

    if (tid < 64) toks[tid] = (m0 + tid < cntE) ? tok_of[base + tid] : 0;

    const float* wgbase = w13 + ((size_t)e * ITR2 + n0) * HID;
    const float* wubase = w13 + ((size_t)e * ITR2 + ITR + n0) * HID;

    float accg[8][4] = {{0.f}};
    float accu[8][4] = {{0.f}};
    const int tn = tid & 31, tm = tid >> 5;

    for (int k0 = 0; k0 < HID; k0 += KC) {
        const float sg = w13s[(e * 22 + (n0 >> 7)) * 16 + (k0 >> 7)];
        const float su = w13s[(e * 22 + ((ITR + n0) >> 7)) * 16 + (k0 >> 7)];
        __syncthreads();
        {   // stage x: 64 tokens x KC
            int kk = tid & 15;
            int m  = tid >> 4;
            #pragma unroll
            for (int p = 0; p < 4; ++p, m += 16)
                xs[kk][m] = x[(size_t)toks[m] * HID + k0 + kk];
        }
        // stage w gate+up: 128 rows x KC each, scale folded in
        #pragma unroll
        for (int q = tid; q < 512; q += 256) {
            int n = q >> 2, kq = (q & 3) * 4;
            float4 g = *(const float4*)&wgbase[(size_t)n * HID + k0 + kq];
            float4 u = *(const float4*)&wubase[(size_t)n * HID + k0 + kq];
            wgs[kq+0][n] = g.x * sg; wgs[kq+1][n] = g.y * sg;
            wgs[kq+2][n] = g.z * sg; wgs[kq+3][n] = g.w * sg;
            wus[kq+0][n] = u.x * su; wus[kq+1][n] = u.y * su;
            wus[kq+2][n] = u.z * su; wus[kq+3][n] = u.w * su;
        }
        __syncthreads();
        #pragma unroll
        for (int k = 0; k < KC; ++k) {
            float4 xa = *(const float4*)&xs[k][tm * 8];
            float4 xb = *(const float4*)&xs[k][tm * 8 + 4];
            float4 g4 = *(const float4*)&wgs[k][tn * 4];
            float4 u4 = *(const float4*)&wus[k][tn * 4];
            float xv[8] = {xa.x, xa.y, xa.z, xa.w, xb.x, xb.y, xb.z, xb.w};
            float gv[4] = {g4.x, g4.y, g4.z, g4.w};
            float uv[4] = {u4.x, u4.y, u4.z, u4.w};
            #pragma unroll
            for (int i = 0; i < 8; ++i)
                #pragma unroll
                for (int j = 0; j < 4; ++j) {
                    accg[i][j] = fmaf(xv[i], gv[j], accg[i][j]);
                    accu[i][j] = fmaf(xv[i], uv[j], accu[i][j]);
                }
        }
    }

    #pragma unroll
    for (int i = 0; i < 8; ++i) {
        int ml = tm * 8 + i;
        if (m0 + ml < cntE) {
            float4 av; float g, u;
            g = accg[i][0]; u = accu[i][0]; av.x = (g / (1.f + expf(-g))) * u;
            g = accg[i][1]; u = accu[i][1]; av.y = (g / (1.f + expf(-g))) * u;
            g = accg[i][2]; u = accu[i][2]; av.z = (g / (1.f + expf(-g))) * u;
            g = accg[i][3]; u = accu[i][3]; av.w = (g / (1.f + expf(-g))) * u;
            *(float4*)&a_buf[(size_t)(base + ml) * ITR + n0 + tn * 4] = av;
        }
    }
}

// ------------- GEMM2: out[t] += wgt * (a @ w2^T * sc) -------------
__global__ __launch_bounds__(256) void k_gemm2(
    const float* __restrict__ a_buf, const float* __restrict__ w2,
    const float* __restrict__ w2s, const int* __restrict__ offs,
    const int* __restrict__ cnt, const int* __restrict__ tok_of,
    const float* __restrict__ w_of, float* __restrict__ out)
{
    const int e = blockIdx.z;
    const int cntE = cnt[e];
    const int m0 = blockIdx.y * 64;
    if (m0 >= cntE) return;
    const int n0 = blockIdx.x * 128;
    const int base = offs[e] + m0;
    const int tid = threadIdx.x;

    __shared__ float as_[KC][68];
    __shared__ float wls[KC][132];
    __shared__ int   toks[64];
    __shared__ float wts[64];

    if (tid < 64) {
        bool valid = (m0 + tid < cntE);
        toks[tid] = valid ? tok_of[base + tid] : 0;
        wts[tid]  = valid ? w_of[base + tid] : 0.f;
    }

    const float* wbase = w2 + ((size_t)e * HID + n0) * ITR;
    float acc[8][4] = {{0.f}};
    const int tn = tid & 31, tm = tid >> 5;

    for (int k0 = 0; k0 < ITR; k0 += KC) {
        const float sc = w2s[(e * 16 + (n0 >> 7)) * 11 + (k0 >> 7)];
        __syncthreads();
        {   // stage a rows (contiguous slots)
            int kk = tid & 15;
            int m  = tid >> 4;
            #pragma unroll
            for (int p = 0; p < 4; ++p, m += 16) {
                int slot = min(base + m, NSLOT - 1);
                as_[kk][m] = a_buf[(size_t)slot * ITR + k0 + kk];
            }
        }
        #pragma unroll
        for (int q = tid; q < 512; q += 256) {
            int n = q >> 2, kq = (q & 3) * 4;
            float4 w4 = *(const float4*)&wbase[(size_t)n * ITR + k0 + kq];
            wls[kq+0][n] = w4.x * sc; wls[kq+1][n] = w4.y * sc;
            wls[kq+2][n] = w4.z * sc; wls[kq+3][n] = w4.w * sc;
        }
        __syncthreads();
        #pragma unroll
        for (int k = 0; k < KC; ++k) {
            float4 xa = *(const float4*)&as_[k][tm * 8];
            float4 xb = *(const float4*)&as_[k][tm * 8 + 4];
            float4 w4 = *(const float4*)&wls[k][tn * 4];
            float xv[8] = {xa.x, xa.y, xa.z, xa.w, xb.x, xb.y, xb.z, xb.w};
            float wv[4] = {w4.x, w4.y, w4.z, w4.w};
            #pragma unroll
            for (int i = 0; i < 8; ++i)
                #pragma unroll
                for (int j = 0; j < 4; ++j)
                    acc[i][j] = fmaf(xv[i], wv[j], acc[i][j]);
        }
    }

    #pragma unroll
    for (int i = 0; i < 8; ++i) {
        int ml = tm * 8 + i;
        if (m0 + ml < cntE) {
            float wgt = wts[ml];
            int t = toks[ml];
            float* po = &out[(size_t)t * HID + n0 + tn * 4];
            atomicAdd(po + 0, acc[i][0] * wgt);
            atomicAdd(po + 1, acc[i][1] * wgt);
            atomicAdd(po + 2, acc[i][2] * wgt);
            atomicAdd(po + 3, acc[i][3] * wgt);
        }
    }
}

extern "C" void kernel_launch(void* const* d_in, const int* in_sizes, int n_in,
                              void* d_out, int out_size, void* d_ws, size_t ws_size,
                              hipStream_t stream)
{
    const float* x      = (const float*)d_in[0];
    const float* logits = (const float*)d_in[1];
    const float* w13    = (const float*)d_in[2];
    const float* w13s   = (const float*)d_in[3];
    const float* w2     = (const float*)d_in[4];
    const float* w2s    = (const float*)d_in[5];
    float* out = (float*)d_out;
    char*  ws  = (char*)d_ws;

    int*   cnt     = (int*)(ws + OFF_CNT);
    int*   cnt2    = (int*)(ws + OFF_CNT2);
    int*   offs    = (int*)(ws + OFF_OFFS);
    int*   top_ids = (int*)(ws + OFF_TOPID);
    float* top_w   = (float*)(ws + OFF_TOPW);
    int*   tok_of  = (int*)(ws + OFF_TOK);
    float* w_of    = (float*)(ws + OFF_WOF);
    float* a_buf   = (float*)(ws + OFF_ABUF);

    hipMemsetAsync(ws, 0, 128, stream);
    hipMemsetAsync(d_out, 0, (size_t)out_size * sizeof(float), stream);

    k_route  <<<T_TOK / 4,   256, 0, stream>>>(logits, cnt, top_ids, top_w);
    k_offsets<<<1,            64, 0, stream>>>(cnt, cnt2, offs);
    k_scatter<<<T_TOK / 256, 256, 0, stream>>>(top_ids, top_w, offs, cnt2, tok_of, w_of);
    k_gemm1  <<<dim3(ITR / 128, 32, NLOC), 256, 0, stream>>>(x, w13, w13s, offs, cnt, tok_of, a_buf);
    k_gemm2  <<<dim3(HID / 128, 32, NLOC), 256, 0, stream>>>(a_buf, w2, w2s, offs, cnt, tok_of, w_of, out);
}

// Round 2
// 219.007 us; speedup vs baseline: 4.3765x; 4.3765x over previous
//
#include <hip/hip_runtime.h>
#include <hip/hip_bf16.h>
#include <cstdint>

#define T_TOK 2048
#define HID   2048
#define NEXP  64
#define TOPK  6
#define NLOC  8
#define ITR   1408
#define ITR2  2816
#define NSLOT (T_TOK * TOPK)

// workspace layout (bytes)
#define OFF_CNT   0
#define OFF_CNT2  32
#define OFF_OFFS  64
#define OFF_TOPID 4096
#define OFF_TOPW  (OFF_TOPID + T_TOK * TOPK * 4)
#define OFF_TOK   (OFF_TOPW  + T_TOK * TOPK * 4)
#define OFF_WOF   (OFF_TOK   + NSLOT * 4)
#define OFF_XBF   (OFF_WOF   + NSLOT * 4)          // 200704, 256-aligned
#define OFF_ABUF  (OFF_XBF   + (size_t)T_TOK * HID * 2)

typedef __attribute__((ext_vector_type(4))) float f32x4;
typedef __attribute__((ext_vector_type(8))) short s16x8;
typedef __attribute__((ext_vector_type(4))) short s16x4;

__device__ __forceinline__ short f2bf(float f) {
    union { float f; unsigned u; } v; v.f = f;
    unsigned r = v.u + 0x7FFFu + ((v.u >> 16) & 1u);
    return (short)(r >> 16);
}

// LDS xor-swizzle on short index (byte bits 4-6) — G4 fix for stride-128B reads
#define SW(idx, row) ((idx) ^ (((row) & 7) << 3))

// ---------------- routing: softmax + top-6 (stable tie-break) ----------------
__global__ __launch_bounds__(256) void k_route(
    const float* __restrict__ logits, int* __restrict__ cnt,
    int* __restrict__ top_ids, float* __restrict__ top_w)
{
    const int lane = threadIdx.x & 63;
    const int t = blockIdx.x * 4 + (threadIdx.x >> 6);

    float v = logits[t * NEXP + lane];
    float m = v;
    #pragma unroll
    for (int s = 32; s > 0; s >>= 1) m = fmaxf(m, __shfl_xor(m, s));
    float ev = expf(v - m);
    float ssum = ev;
    #pragma unroll
    for (int s = 32; s > 0; s >>= 1) ssum += __shfl_xor(ssum, s);
    float p = ev / ssum;

    float pv = p;
    int ids[TOPK]; float wsel[TOPK]; float wsum = 0.f;
    #pragma unroll
    for (int i = 0; i < TOPK; ++i) {
        float mx = pv;
        #pragma unroll
        for (int s = 32; s > 0; s >>= 1) mx = fmaxf(mx, __shfl_xor(mx, s));
        unsigned long long b = __ballot(pv == mx);
        int idx = (int)__builtin_ctzll(b);
        float w = __shfl(p, idx);
        ids[i] = idx; wsel[i] = w; wsum += w;
        if (lane == idx) pv = -1.0f;
    }
    if (lane < TOPK) {
        top_ids[t * TOPK + lane] = ids[lane];
        top_w[t * TOPK + lane]  = wsel[lane] / wsum;
    }
    if (lane == 0) {
        #pragma unroll
        for (int i = 0; i < TOPK; ++i)
            if ((ids[i] & 7) == 0) atomicAdd(&cnt[ids[i] >> 3], 1);
    }
}

__global__ void k_offsets(int* __restrict__ cnt, int* __restrict__ cnt2,
                          int* __restrict__ offs)
{
    if (threadIdx.x == 0) {
        int s = 0;
        for (int e = 0; e < NLOC; ++e) { offs[e] = s; s += cnt[e]; cnt2[e] = 0; }
    }
}

__global__ __launch_bounds__(256) void k_scatter(
    const int* __restrict__ top_ids, const float* __restrict__ top_w,
    const int* __restrict__ offs, int* __restrict__ cnt2,
    int* __restrict__ tok_of, float* __restrict__ w_of)
{
    const int t = blockIdx.x * 256 + threadIdx.x;
    #pragma unroll
    for (int i = 0; i < TOPK; ++i) {
        int id = top_ids[t * TOPK + i];
        if ((id & 7) == 0) {
            int e = id >> 3;
            int s = offs[e] + atomicAdd(&cnt2[e], 1);
            tok_of[s] = t;
            w_of[s]  = top_w[t * TOPK + i];
        }
    }
}

// ---------------- x fp32 -> bf16 once ----------------
__global__ __launch_bounds__(256) void k_cvt_x(const float* __restrict__ x,
                                               short* __restrict__ xbf)
{
    const int r = blockIdx.x;
    const int c = threadIdx.x * 8;
    const float4 a = *(const float4*)&x[(size_t)r * HID + c];
    const float4 b = *(const float4*)&x[(size_t)r * HID + c + 4];
    s16x8 v = { f2bf(a.x), f2bf(a.y), f2bf(a.z), f2bf(a.w),
                f2bf(b.x), f2bf(b.y), f2bf(b.z), f2bf(b.w) };
    *(s16x8*)&xbf[(size_t)r * HID + c] = v;
}

// ------------- GEMM1: a = silu(x@w13g^T*sg) * (x@w13u^T*su), bf16 MFMA -------------
// tile M=64 slots x NP=64 pair-cols (64 gate rows + 64 up rows), K-step 64, dbuf LDS
__global__ __launch_bounds__(256, 3) void k_gemm1(
    const short* __restrict__ xbf, const float* __restrict__ w13,
    const float* __restrict__ w13s, const int* __restrict__ offs,
    const int* __restrict__ cnt, const int* __restrict__ tok_of,
    short* __restrict__ a_buf)
{
    const int e = blockIdx.z;
    const int cntE = cnt[e];
    const int m0 = blockIdx.y * 64;
    if (m0 >= cntE) return;
    const int n0 = blockIdx.x * 64;
    const int base = offs[e] + m0;
    const int tid = threadIdx.x;
    const int lane = tid & 63;
    const int wid = tid >> 6, wm = wid >> 1, wn = wid & 1;

    __shared__ __align__(16) short As[2][64 * 64];
    __shared__ __align__(16) short Ws[2][128 * 64];
    __shared__ int toks[64];

    if (tid < 64) toks[tid] = tok_of[base + ((m0 + tid < cntE) ? tid : 0)];
    __syncthreads();

    const int ar_ = tid >> 3;          // A stage: rows ar_, ar_+32
    const int ac_ = (tid & 7) * 8;     // col (shorts)
    const int wr_ = tid >> 4;          // W stage: rows wr_+16p
    const int wc_ = (tid & 15) * 4;    // col (floats)
    const int t0r = toks[ar_], t1r = toks[ar_ + 32];

    const float* wg = w13 + ((size_t)e * ITR2 + n0) * HID;
    const float* wu = w13 + ((size_t)e * ITR2 + ITR + n0) * HID;
    const int sgi = (e * 22 + (n0 >> 7)) * 16;
    const int sui = (e * 22 + ((ITR + n0) >> 7)) * 16;

    s16x8 ar0, ar1;
    float4 wrg[8];
    float sgv, suv;
    f32x4 acc[2][2][2] = {};   // [t][nf][mf]

#define G1_LOAD(kk) do {                                                      \
    const int k0 = (kk) * 64;                                                 \
    sgv = w13s[sgi + ((kk) >> 1)];                                            \
    suv = w13s[sui + ((kk) >> 1)];                                            \
    ar0 = *(const s16x8*)&xbf[(size_t)t0r * HID + k0 + ac_];                  \
    ar1 = *(const s16x8*)&xbf[(size_t)t1r * HID + k0 + ac_];                  \
    _Pragma("unroll")                                                         \
    for (int p = 0; p < 4; ++p)                                               \
        wrg[p] = *(const float4*)&wg[(size_t)(wr_ + p * 16) * HID + k0 + wc_];\
    _Pragma("unroll")                                                         \
    for (int p = 0; p < 4; ++p)                                               \
        wrg[4 + p] = *(const float4*)&wu[(size_t)(wr_ + p * 16) * HID + k0 + wc_];\
} while (0)

#define G1_WRITE(b) do {                                                      \
    *(s16x8*)&As[b][SW(ar_ * 64 + ac_, ar_)] = ar0;                           \
    *(s16x8*)&As[b][SW((ar_ + 32) * 64 + ac_, ar_ + 32)] = ar1;               \
    _Pragma("unroll")                                                         \
    for (int p = 0; p < 8; ++p) {                                             \
        const int row = (p < 4) ? (wr_ + p * 16) : (64 + wr_ + (p - 4) * 16); \
        const float s = (p < 4) ? sgv : suv;                                  \
        s16x4 v = { f2bf(wrg[p].x * s), f2bf(wrg[p].y * s),                   \
                    f2bf(wrg[p].z * s), f2bf(wrg[p].w * s) };                 \
        *(s16x4*)&Ws[b][SW(row * 64 + wc_, row)] = v;                         \
    }                                                                         \
} while (0)

#define G1_COMP(b) do {                                                       \
    _Pragma("unroll")                                                         \
    for (int ks = 0; ks < 2; ++ks) {                                          \
        const int co = ks * 32 + (lane >> 4) * 8;                             \
        s16x8 af[2];                                                          \
        _Pragma("unroll")                                                     \
        for (int mf = 0; mf < 2; ++mf) {                                      \
            const int row = wm * 32 + mf * 16 + (lane & 15);                  \
            af[mf] = *(const s16x8*)&As[b][SW(row * 64 + co, row)];           \
        }                                                                     \
        _Pragma("unroll")                                                     \
        for (int tt = 0; tt < 2; ++tt)                                        \
        _Pragma("unroll")                                                     \
        for (int nf = 0; nf < 2; ++nf) {                                      \
            const int row = tt * 64 + wn * 32 + nf * 16 + (lane & 15);        \
            s16x8 bv = *(const s16x8*)&Ws[b][SW(row * 64 + co, row)];         \
            acc[tt][nf][0] = __builtin_amdgcn_mfma_f32_16x16x32_bf16(af[0], bv, acc[tt][nf][0], 0, 0, 0); \
            acc[tt][nf][1] = __builtin_amdgcn_mfma_f32_16x16x32_bf16(af[1], bv, acc[tt][nf][1], 0, 0, 0); \
        }                                                                     \
    }                                                                         \
} while (0)

    G1_LOAD(0);
    G1_WRITE(0);
    __syncthreads();
    for (int k = 0; k < 32; ++k) {
        const int cur = k & 1;
        if (k + 1 < 32) G1_LOAD(k + 1);
        G1_COMP(cur);
        if (k + 1 < 32) G1_WRITE(cur ^ 1);
        __syncthreads();
    }

    // epilogue: silu(gate)*up -> a_buf bf16
    #pragma unroll
    for (int nf = 0; nf < 2; ++nf) {
        const int col = n0 + wn * 32 + nf * 16 + (lane & 15);
        #pragma unroll
        for (int mf = 0; mf < 2; ++mf)
        #pragma unroll
        for (int j = 0; j < 4; ++j) {
            const int row = wm * 32 + mf * 16 + (lane >> 4) * 4 + j;
            if (m0 + row < cntE) {
                const float g = acc[0][nf][mf][j], u = acc[1][nf][mf][j];
                const float a = (g / (1.f + __expf(-g))) * u;
                a_buf[(size_t)(base + row) * ITR + col] = f2bf(a);
            }
        }
    }
#undef G1_LOAD
#undef G1_WRITE
#undef G1_COMP
}

// ------------- GEMM2: out[t] += wgt * (a @ w2^T * sc), bf16 MFMA -------------
__global__ __launch_bounds__(256, 3) void k_gemm2(
    const short* __restrict__ a_buf, const float* __restrict__ w2,
    const float* __restrict__ w2s, const int* __restrict__ offs,
    const int* __restrict__ cnt, const int* __restrict__ tok_of,
    const float* __restrict__ w_of, float* __restrict__ out)
{
    const int e = blockIdx.z;
    const int cntE = cnt[e];
    const int m0 = blockIdx.y * 64;
    if (m0 >= cntE) return;
    const int n0 = blockIdx.x * 64;
    const int base = offs[e] + m0;
    const int tid = threadIdx.x;
    const int lane = tid & 63;
    const int wid = tid >> 6, wm = wid >> 1, wn = wid & 1;

    __shared__ __align__(16) short As[2][64 * 64];
    __shared__ __align__(16) short Ws[2][64 * 64];
    __shared__ int toks[64];
    __shared__ float wts[64];

    if (tid < 64) {
        const bool v = (m0 + tid < cntE);
        toks[tid] = v ? tok_of[base + tid] : 0;
        wts[tid]  = v ? w_of[base + tid] : 0.f;
    }
    __syncthreads();

    const int ar_ = tid >> 3;
    const int ac_ = (tid & 7) * 8;
    const int wr_ = tid >> 4;
    const int wc_ = (tid & 15) * 4;
    const int arow0 = base + ((m0 + ar_ < cntE) ? ar_ : 0);
    const int arow1 = base + ((m0 + ar_ + 32 < cntE) ? ar_ + 32 : 0);

    const float* wb = w2 + ((size_t)e * HID + n0) * ITR;
    const int sci = (e * 16 + (n0 >> 7)) * 11;

    s16x8 ar0, ar1;
    float4 wrg[4];
    float scv;
    f32x4 acc[2][2] = {};   // [nf][mf]

#define G2_LOAD(kk) do {                                                      \
    const int k0 = (kk) * 64;                                                 \
    scv = w2s[sci + ((kk) >> 1)];                                             \
    ar0 = *(const s16x8*)&a_buf[(size_t)arow0 * ITR + k0 + ac_];              \
    ar1 = *(const s16x8*)&a_buf[(size_t)arow1 * ITR + k0 + ac_];              \
    _Pragma("unroll")                                                         \
    for (int p = 0; p < 4; ++p)                                               \
        wrg[p] = *(const float4*)&wb[(size_t)(wr_ + p * 16) * ITR + k0 + wc_];\
} while (0)

#define G2_WRITE(b) do {                                                      \
    *(s16x8*)&As[b][SW(ar_ * 64 + ac_, ar_)] = ar0;                           \
    *(s16x8*)&As[b][SW((ar_ + 32) * 64 + ac_, ar_ + 32)] = ar1;               \
    _Pragma("unroll")                                                         \
    for (int p = 0; p < 4; ++p) {                                             \
        const int row = wr_ + p * 16;                                         \
        s16x4 v = { f2bf(wrg[p].x * scv), f2bf(wrg[p].y * scv),               \
                    f2bf(wrg[p].z * scv), f2bf(wrg[p].w * scv) };             \
        *(s16x4*)&Ws[b][SW(row * 64 + wc_, row)] = v;                         \
    }                                                                         \
} while (0)

#define G2_COMP(b) do {                                                       \
    _Pragma("unroll")                                                         \
    for (int ks = 0; ks < 2; ++ks) {                                          \
        const int co = ks * 32 + (lane >> 4) * 8;                             \
        s16x8 af[2];                                                          \
        _Pragma("unroll")                                                     \
        for (int mf = 0; mf < 2; ++mf) {                                      \
            const int row = wm * 32 + mf * 16 + (lane & 15);                  \
            af[mf] = *(const s16x8*)&As[b][SW(row * 64 + co, row)];           \
        }                                                                     \
        _Pragma("unroll")                                                     \
        for (int nf = 0; nf < 2; ++nf) {                                      \
            const int row = wn * 32 + nf * 16 + (lane & 15);                  \
            s16x8 bv = *(const s16x8*)&Ws[b][SW(row * 64 + co, row)];         \
            acc[nf][0] = __builtin_amdgcn_mfma_f32_16x16x32_bf16(af[0], bv, acc[nf][0], 0, 0, 0); \
            acc[nf][1] = __builtin_amdgcn_mfma_f32_16x16x32_bf16(af[1], bv, acc[nf][1], 0, 0, 0); \
        }                                                                     \
    }                                                                         \
} while (0)

    G2_LOAD(0);
    G2_WRITE(0);
    __syncthreads();
    for (int k = 0; k < 22; ++k) {
        const int cur = k & 1;
        if (k + 1 < 22) G2_LOAD(k + 1);
        G2_COMP(cur);
        if (k + 1 < 22) G2_WRITE(cur ^ 1);
        __syncthreads();
    }

    #pragma unroll
    for (int nf = 0; nf < 2; ++nf) {
        const int col = n0 + wn * 32 + nf * 16 + (lane & 15);
        #pragma unroll
        for (int mf = 0; mf < 2; ++mf)
        #pragma unroll
        for (int j = 0; j < 4; ++j) {
            const int row = wm * 32 + mf * 16 + (lane >> 4) * 4 + j;
            if (m0 + row < cntE)
                atomicAdd(&out[(size_t)toks[row] * HID + col], acc[nf][mf][j] * wts[row]);
        }
    }
#undef G2_LOAD
#undef G2_WRITE
#undef G2_COMP
}

extern "C" void kernel_launch(void* const* d_in, const int* in_sizes, int n_in,
                              void* d_out, int out_size, void* d_ws, size_t ws_size,
                              hipStream_t stream)
{
    const float* x      = (const float*)d_in[0];
    const float* logits = (const float*)d_in[1];
    const float* w13    = (const float*)d_in[2];
    const float* w13s   = (const float*)d_in[3];
    const float* w2     = (const float*)d_in[4];
    const float* w2s    = (const float*)d_in[5];
    float* out = (float*)d_out;
    char*  ws  = (char*)d_ws;

    int*   cnt     = (int*)(ws + OFF_CNT);
    int*   cnt2    = (int*)(ws + OFF_CNT2);
    int*   offs    = (int*)(ws + OFF_OFFS);
    int*   top_ids = (int*)(ws + OFF_TOPID);
    float* top_w   = (float*)(ws + OFF_TOPW);
    int*   tok_of  = (int*)(ws + OFF_TOK);
    float* w_of    = (float*)(ws + OFF_WOF);
    short* xbf     = (short*)(ws + OFF_XBF);
    short* a_buf   = (short*)(ws + OFF_ABUF);

    hipMemsetAsync(ws, 0, 128, stream);
    hipMemsetAsync(d_out, 0, (size_t)out_size * sizeof(float), stream);

    k_route  <<<T_TOK / 4,   256, 0, stream>>>(logits, cnt, top_ids, top_w);
    k_offsets<<<1,            64, 0, stream>>>(cnt, cnt2, offs);
    k_scatter<<<T_TOK / 256, 256, 0, stream>>>(top_ids, top_w, offs, cnt2, tok_of, w_of);
    k_cvt_x  <<<T_TOK,       256, 0, stream>>>(x, xbf);
    k_gemm1  <<<dim3(22, 10, NLOC), 256, 0, stream>>>(xbf, w13, w13s, offs, cnt, tok_of, a_buf);
    k_gemm2  <<<dim3(32, 10, NLOC), 256, 0, stream>>>(a_buf, w2, w2s, offs, cnt, tok_of, w_of, out);
}

// Round 3
// 171.932 us; speedup vs baseline: 5.5748x; 1.2738x over previous
//
#include <hip/hip_runtime.h>
#include <hip/hip_bf16.h>
#include <cstdint>

#define T_TOK 2048
#define HID   2048
#define NEXP  64
#define TOPK  6
#define NLOC  8
#define ITR   1408
#define ITR2  2816
#define NSLOT (T_TOK * TOPK)
#define NK1   32   // HID/64
#define NK2   22   // ITR/64

// workspace layout (bytes)
#define OFF_CNT   0
#define OFF_CNT2  32
#define OFF_OFFS  64
#define OFF_TOPID 4096
#define OFF_TOPW  (OFF_TOPID + T_TOK * TOPK * 4)
#define OFF_TOK   (OFF_TOPW  + T_TOK * TOPK * 4)
#define OFF_WOF   (OFF_TOK   + NSLOT * 4)
#define OFF_XBF   (OFF_WOF   + NSLOT * 4)
#define OFF_ABUF  (OFF_XBF   + (size_t)T_TOK * HID * 2)

typedef __attribute__((ext_vector_type(4))) float f32x4;
typedef __attribute__((ext_vector_type(8))) short s16x8;
typedef __attribute__((ext_vector_type(4))) short s16x4;

__device__ __forceinline__ short f2bf(float f) {
    union { float f; unsigned u; } v; v.f = f;
    unsigned r = v.u + 0x7FFFu + ((v.u >> 16) & 1u);
    return (short)(r >> 16);
}

// ---------------- routing: softmax + top-6 (stable tie-break) ----------------
__global__ __launch_bounds__(256) void k_route(
    const float* __restrict__ logits, int* __restrict__ cnt,
    int* __restrict__ top_ids, float* __restrict__ top_w)
{
    const int lane = threadIdx.x & 63;
    const int t = blockIdx.x * 4 + (threadIdx.x >> 6);

    float v = logits[t * NEXP + lane];
    float m = v;
    #pragma unroll
    for (int s = 32; s > 0; s >>= 1) m = fmaxf(m, __shfl_xor(m, s));
    float ev = expf(v - m);
    float ssum = ev;
    #pragma unroll
    for (int s = 32; s > 0; s >>= 1) ssum += __shfl_xor(ssum, s);
    float p = ev / ssum;

    float pv = p;
    int ids[TOPK]; float wsel[TOPK]; float wsum = 0.f;
    #pragma unroll
    for (int i = 0; i < TOPK; ++i) {
        float mx = pv;
        #pragma unroll
        for (int s = 32; s > 0; s >>= 1) mx = fmaxf(mx, __shfl_xor(mx, s));
        unsigned long long b = __ballot(pv == mx);
        int idx = (int)__builtin_ctzll(b);
        float w = __shfl(p, idx);
        ids[i] = idx; wsel[i] = w; wsum += w;
        if (lane == idx) pv = -1.0f;
    }
    if (lane < TOPK) {
        top_ids[t * TOPK + lane] = ids[lane];
        top_w[t * TOPK + lane]  = wsel[lane] / wsum;
    }
    if (lane == 0) {
        #pragma unroll
        for (int i = 0; i < TOPK; ++i)
            if ((ids[i] & 7) == 0) atomicAdd(&cnt[ids[i] >> 3], 1);
    }
}

__global__ void k_offsets(int* __restrict__ cnt, int* __restrict__ cnt2,
                          int* __restrict__ offs)
{
    if (threadIdx.x == 0) {
        int s = 0;
        for (int e = 0; e < NLOC; ++e) { offs[e] = s; s += cnt[e]; cnt2[e] = 0; }
    }
}

__global__ __launch_bounds__(256) void k_scatter(
    const int* __restrict__ top_ids, const float* __restrict__ top_w,
    const int* __restrict__ offs, int* __restrict__ cnt2,
    int* __restrict__ tok_of, float* __restrict__ w_of)
{
    const int t = blockIdx.x * 256 + threadIdx.x;
    #pragma unroll
    for (int i = 0; i < TOPK; ++i) {
        int id = top_ids[t * TOPK + i];
        if ((id & 7) == 0) {
            int e = id >> 3;
            int s = offs[e] + atomicAdd(&cnt2[e], 1);
            tok_of[s] = t;
            w_of[s]  = top_w[t * TOPK + i];
        }
    }
}

// ---------------- x fp32 -> bf16 once ----------------
__global__ __launch_bounds__(256) void k_cvt_x(const float* __restrict__ x,
                                               short* __restrict__ xbf)
{
    const int r = blockIdx.x;
    const int c = threadIdx.x * 8;
    const float4 a = *(const float4*)&x[(size_t)r * HID + c];
    const float4 b = *(const float4*)&x[(size_t)r * HID + c + 4];
    s16x8 v = { f2bf(a.x), f2bf(a.y), f2bf(a.z), f2bf(a.w),
                f2bf(b.x), f2bf(b.y), f2bf(b.z), f2bf(b.w) };
    *(s16x8*)&xbf[(size_t)r * HID + c] = v;
}

// ------------- GEMM1: M=256 (all tokens of expert) x N=32 pair-cols, K-step 64 -------------
__global__ __launch_bounds__(256, 2) void k_gemm1(
    const short* __restrict__ xbf, const float* __restrict__ w13,
    const float* __restrict__ w13s, const int* __restrict__ offs,
    const int* __restrict__ cnt, const int* __restrict__ tok_of,
    short* __restrict__ a_buf)
{
    const int e = blockIdx.z;
    const int cntE = cnt[e];
    const int m0 = blockIdx.y * 256;
    if (m0 >= cntE) return;
    const int n0p = blockIdx.x * 32;          // pair-col base in [0, ITR)
    const int base = offs[e] + m0;
    const int tid = threadIdx.x;
    const int lane = tid & 63;
    const int wm = tid >> 6;                  // wave id 0..3 -> owns rows wm*64..+63

    __shared__ __align__(16) short As[2][256 * 64];   // 64 KB
    __shared__ __align__(16) short Ws[2][64 * 64];    // 16 KB (32 gate + 32 up rows)

    // stage token ids through As[0] (reused before first WRITE)
    int* tokp = (int*)&As[0][0];
    tokp[tid] = tok_of[base + ((m0 + tid < cntE) ? tid : 0)];
    __syncthreads();

    const short* aptr[8];
    int aoff[8];
    #pragma unroll
    for (int p = 0; p < 8; ++p) {
        const int row = p * 32 + (tid >> 3), cg = tid & 7;
        aptr[p] = xbf + (size_t)tokp[row] * HID + cg * 8;
        aoff[p] = (row * 64 + cg * 8) ^ ((row & 7) << 3);
    }
    __syncthreads();   // done reading tokp; As[0] free for staging

    const float* wptr[4];
    int woff[4];
    {
        const float* wg = w13 + ((size_t)e * ITR2 + n0p) * HID;
        const float* wu = w13 + ((size_t)e * ITR2 + ITR + n0p) * HID;
        #pragma unroll
        for (int p = 0; p < 4; ++p) {
            const int row = p * 16 + (tid >> 4), ch = tid & 15;
            wptr[p] = ((p < 2) ? wg : wu) + (size_t)(row & 31) * HID + ch * 4;
            woff[p] = (row * 64 + ch * 4) ^ ((row & 7) << 3);
        }
    }
    const int sgi = (e * 22 + (n0p >> 7)) * 16;
    const int sui = (e * 22 + 11 + (n0p >> 7)) * 16;

    s16x8 ra[8];
    float4 rw[4];
    float sgv, suv;
    f32x4 acc[2][2][4] = {};    // [gate/up][nf][mf]

#define G1_LOAD(kk) do {                                                       \
    const int k0 = (kk) * 64;                                                  \
    sgv = w13s[sgi + ((kk) >> 1)];                                             \
    suv = w13s[sui + ((kk) >> 1)];                                             \
    _Pragma("unroll")                                                          \
    for (int p = 0; p < 8; ++p) ra[p] = *(const s16x8*)(aptr[p] + k0);         \
    _Pragma("unroll")                                                          \
    for (int p = 0; p < 4; ++p) rw[p] = *(const float4*)(wptr[p] + k0);        \
} while (0)

#define G1_WRITE(b) do {                                                       \
    _Pragma("unroll")                                                          \
    for (int p = 0; p < 8; ++p) *(s16x8*)&As[b][aoff[p]] = ra[p];              \
    _Pragma("unroll")                                                          \
    for (int p = 0; p < 4; ++p) {                                              \
        const float s = (p < 2) ? sgv : suv;                                   \
        s16x4 v = { f2bf(rw[p].x * s), f2bf(rw[p].y * s),                      \
                    f2bf(rw[p].z * s), f2bf(rw[p].w * s) };                    \
        *(s16x4*)&Ws[b][woff[p]] = v;                                          \
    }                                                                          \
} while (0)

#define G1_COMP(b) do {                                                        \
    _Pragma("unroll")                                                          \
    for (int ks = 0; ks < 2; ++ks) {                                           \
        const int co = ks * 32 + (lane >> 4) * 8;                              \
        s16x8 af[4];                                                           \
        _Pragma("unroll")                                                      \
        for (int mf = 0; mf < 4; ++mf) {                                       \
            const int row = wm * 64 + mf * 16 + (lane & 15);                   \
            af[mf] = *(const s16x8*)&As[b][(row * 64 + co) ^ ((row & 7) << 3)];\
        }                                                                      \
        _Pragma("unroll")                                                      \
        for (int t = 0; t < 2; ++t)                                            \
        _Pragma("unroll")                                                      \
        for (int nf = 0; nf < 2; ++nf) {                                       \
            const int row = t * 32 + nf * 16 + (lane & 15);                    \
            s16x8 bv = *(const s16x8*)&Ws[b][(row * 64 + co) ^ ((row & 7) << 3)];\
            _Pragma("unroll")                                                  \
            for (int mf = 0; mf < 4; ++mf)                                     \
                acc[t][nf][mf] = __builtin_amdgcn_mfma_f32_16x16x32_bf16(af[mf], bv, acc[t][nf][mf], 0, 0, 0); \
        }                                                                      \
    }                                                                          \
} while (0)

    G1_LOAD(0);
    G1_WRITE(0);
    __syncthreads();
    #pragma unroll 2
    for (int k = 0; k < NK1; ++k) {
        if (k + 1 < NK1) G1_LOAD(k + 1);
        G1_COMP(k & 1);
        if (k + 1 < NK1) {
            G1_WRITE((k & 1) ^ 1);
            __syncthreads();
        }
    }

    // epilogue: silu(gate)*up -> a_buf bf16
    #pragma unroll
    for (int nf = 0; nf < 2; ++nf) {
        const int col = n0p + nf * 16 + (lane & 15);
        #pragma unroll
        for (int mf = 0; mf < 4; ++mf)
        #pragma unroll
        for (int j = 0; j < 4; ++j) {
            const int row = wm * 64 + mf * 16 + (lane >> 4) * 4 + j;
            if (m0 + row < cntE) {
                const float g = acc[0][nf][mf][j], u = acc[1][nf][mf][j];
                const float a = (g / (1.f + __expf(-g))) * u;
                a_buf[(size_t)(base + row) * ITR + col] = f2bf(a);
            }
        }
    }
#undef G1_LOAD
#undef G1_WRITE
#undef G1_COMP
}

// ------------- GEMM2: M=256 x N=32 out-cols, K=1408 -------------
__global__ __launch_bounds__(256, 2) void k_gemm2(
    const short* __restrict__ a_buf, const float* __restrict__ w2,
    const float* __restrict__ w2s, const int* __restrict__ offs,
    const int* __restrict__ cnt, const int* __restrict__ tok_of,
    const float* __restrict__ w_of, float* __restrict__ out)
{
    const int e = blockIdx.z;
    const int cntE = cnt[e];
    const int m0 = blockIdx.y * 256;
    if (m0 >= cntE) return;
    const int n0 = blockIdx.x * 32;
    const int base = offs[e] + m0;
    const int tid = threadIdx.x;
    const int lane = tid & 63;
    const int wm = tid >> 6;

    __shared__ __align__(16) short As[2][256 * 64];   // 64 KB
    __shared__ __align__(16) short Ws[2][32 * 64];    // 8 KB

    const short* aptr[8];
    int aoff[8];
    #pragma unroll
    for (int p = 0; p < 8; ++p) {
        const int row = p * 32 + (tid >> 3), cg = tid & 7;
        int srow = base + row; if (srow > NSLOT - 1) srow = NSLOT - 1;
        aptr[p] = a_buf + (size_t)srow * ITR + cg * 8;
        aoff[p] = (row * 64 + cg * 8) ^ ((row & 7) << 3);
    }
    const float* wptr[2];
    int woff[2];
    #pragma unroll
    for (int p = 0; p < 2; ++p) {
        const int row = p * 16 + (tid >> 4), ch = tid & 15;
        wptr[p] = w2 + ((size_t)e * HID + n0 + row) * ITR + ch * 4;
        woff[p] = (row * 64 + ch * 4) ^ ((row & 7) << 3);
    }
    const int sci = (e * 16 + (n0 >> 7)) * 11;

    s16x8 ra[8];
    float4 rw[2];
    float scv;
    f32x4 acc[2][4] = {};    // [nf][mf]

#define G2_LOAD(kk) do {                                                       \
    const int k0 = (kk) * 64;                                                  \
    scv = w2s[sci + ((kk) >> 1)];                                              \
    _Pragma("unroll")                                                          \
    for (int p = 0; p < 8; ++p) ra[p] = *(const s16x8*)(aptr[p] + k0);         \
    _Pragma("unroll")                                                          \
    for (int p = 0; p < 2; ++p) rw[p] = *(const float4*)(wptr[p] + k0);        \
} while (0)

#define G2_WRITE(b) do {                                                       \
    _Pragma("unroll")                                                          \
    for (int p = 0; p < 8; ++p) *(s16x8*)&As[b][aoff[p]] = ra[p];              \
    _Pragma("unroll")                                                          \
    for (int p = 0; p < 2; ++p) {                                              \
        s16x4 v = { f2bf(rw[p].x * scv), f2bf(rw[p].y * scv),                  \
                    f2bf(rw[p].z * scv), f2bf(rw[p].w * scv) };                \
        *(s16x4*)&Ws[b][woff[p]] = v;                                          \
    }                                                                          \
} while (0)

#define G2_COMP(b) do {                                                        \
    _Pragma("unroll")                                                          \
    for (int ks = 0; ks < 2; ++ks) {                                           \
        const int co = ks * 32 + (lane >> 4) * 8;                              \
        s16x8 af[4];                                                           \
        _Pragma("unroll")                                                      \
        for (int mf = 0; mf < 4; ++mf) {                                       \
            const int row = wm * 64 + mf * 16 + (lane & 15);                   \
            af[mf] = *(const s16x8*)&As[b][(row * 64 + co) ^ ((row & 7) << 3)];\
        }                                                                      \
        _Pragma("unroll")                                                      \
        for (int nf = 0; nf < 2; ++nf) {                                       \
            const int row = nf * 16 + (lane & 15);                             \
            s16x8 bv = *(const s16x8*)&Ws[b][(row * 64 + co) ^ ((row & 7) << 3)];\
            _Pragma("unroll")                                                  \
            for (int mf = 0; mf < 4; ++mf)                                     \
                acc[nf][mf] = __builtin_amdgcn_mfma_f32_16x16x32_bf16(af[mf], bv, acc[nf][mf], 0, 0, 0); \
        }                                                                      \
    }                                                                          \
} while (0)

    G2_LOAD(0);
    G2_WRITE(0);
    __syncthreads();
    #pragma unroll 2
    for (int k = 0; k < NK2; ++k) {
        if (k + 1 < NK2) G2_LOAD(k + 1);
        G2_COMP(k & 1);
        if (k + 1 < NK2) {
            G2_WRITE((k & 1) ^ 1);
            __syncthreads();
        }
    }

    #pragma unroll
    for (int mf = 0; mf < 4; ++mf)
    #pragma unroll
    for (int j = 0; j < 4; ++j) {
        const int row = wm * 64 + mf * 16 + (lane >> 4) * 4 + j;
        if (m0 + row < cntE) {
            const int   t = tok_of[base + row];
            const float w = w_of[base + row];
            #pragma unroll
            for (int nf = 0; nf < 2; ++nf) {
                const int col = n0 + nf * 16 + (lane & 15);
                atomicAdd(&out[(size_t)t * HID + col], acc[nf][mf][j] * w);
            }
        }
    }
#undef G2_LOAD
#undef G2_WRITE
#undef G2_COMP
}

extern "C" void kernel_launch(void* const* d_in, const int* in_sizes, int n_in,
                              void* d_out, int out_size, void* d_ws, size_t ws_size,
                              hipStream_t stream)
{
    const float* x      = (const float*)d_in[0];
    const float* logits = (const float*)d_in[1];
    const float* w13    = (const float*)d_in[2];
    const float* w13s   = (const float*)d_in[3];
    const float* w2     = (const float*)d_in[4];
    const float* w2s    = (const float*)d_in[5];
    float* out = (float*)d_out;
    char*  ws  = (char*)d_ws;

    int*   cnt     = (int*)(ws + OFF_CNT);
    int*   cnt2    = (int*)(ws + OFF_CNT2);
    int*   offs    = (int*)(ws + OFF_OFFS);
    int*   top_ids = (int*)(ws + OFF_TOPID);
    float* top_w   = (float*)(ws + OFF_TOPW);
    int*   tok_of  = (int*)(ws + OFF_TOK);
    float* w_of    = (float*)(ws + OFF_WOF);
    short* xbf     = (short*)(ws + OFF_XBF);
    short* a_buf   = (short*)(ws + OFF_ABUF);

    hipMemsetAsync(ws, 0, 128, stream);
    hipMemsetAsync(d_out, 0, (size_t)out_size * sizeof(float), stream);

    k_route  <<<T_TOK / 4,   256, 0, stream>>>(logits, cnt, top_ids, top_w);
    k_offsets<<<1,            64, 0, stream>>>(cnt, cnt2, offs);
    k_scatter<<<T_TOK / 256, 256, 0, stream>>>(top_ids, top_w, offs, cnt2, tok_of, w_of);
    k_cvt_x  <<<T_TOK,       256, 0, stream>>>(x, xbf);
    k_gemm1  <<<dim3(44, 8, NLOC), 256, 0, stream>>>(xbf, w13, w13s, offs, cnt, tok_of, a_buf);
    k_gemm2  <<<dim3(64, 8, NLOC), 256, 0, stream>>>(a_buf, w2, w2s, offs, cnt, tok_of, w_of, out);
}

// Round 4
// 169.387 us; speedup vs baseline: 5.6586x; 1.0150x over previous
//
#include <hip/hip_runtime.h>
#include <hip/hip_bf16.h>
#include <cstdint>

#define T_TOK 2048
#define HID   2048
#define NEXP  64
#define TOPK  6
#define NLOC  8
#define ITR   1408
#define ITR2  2816
#define NSLOT (T_TOK * TOPK)
#define NK1   32   // HID/64
#define NK2   22   // ITR/64

// workspace layout (bytes)
#define OFF_CNT   0
#define OFF_CNT2  32
#define OFF_OFFS  64
#define OFF_TOPID 4096
#define OFF_TOPW  (OFF_TOPID + T_TOK * TOPK * 4)
#define OFF_TOK   (OFF_TOPW  + T_TOK * TOPK * 4)
#define OFF_WOF   (OFF_TOK   + NSLOT * 4)
#define OFF_XBF   (OFF_WOF   + NSLOT * 4)
#define OFF_ABUF  (OFF_XBF   + (size_t)T_TOK * HID * 2)

typedef __attribute__((ext_vector_type(4))) float f32x4;
typedef __attribute__((ext_vector_type(8))) short s16x8;
typedef __attribute__((ext_vector_type(4))) short s16x4;

__device__ __forceinline__ short f2bf(float f) {
    union { float f; unsigned u; } v; v.f = f;
    unsigned r = v.u + 0x7FFFu + ((v.u >> 16) & 1u);
    return (short)(r >> 16);
}

// ---------------- zero d_out + routing counters (replaces slow rocclr fill) ----------------
__global__ __launch_bounds__(256) void k_zero(float* __restrict__ out,
                                              int* __restrict__ cnt)
{
    const int idx = blockIdx.x * 256 + threadIdx.x;   // 262144 threads
    float4 z = {0.f, 0.f, 0.f, 0.f};
    #pragma unroll
    for (int p = 0; p < 4; ++p)
        *(float4*)&out[(size_t)(idx + p * 262144) * 4] = z;
    if (blockIdx.x == 0 && threadIdx.x < 16) cnt[threadIdx.x] = 0;
}

// ---------------- routing: softmax + top-6 (stable tie-break) ----------------
__global__ __launch_bounds__(256) void k_route(
    const float* __restrict__ logits, int* __restrict__ cnt,
    int* __restrict__ top_ids, float* __restrict__ top_w)
{
    const int lane = threadIdx.x & 63;
    const int t = blockIdx.x * 4 + (threadIdx.x >> 6);

    float v = logits[t * NEXP + lane];
    float m = v;
    #pragma unroll
    for (int s = 32; s > 0; s >>= 1) m = fmaxf(m, __shfl_xor(m, s));
    float ev = expf(v - m);
    float ssum = ev;
    #pragma unroll
    for (int s = 32; s > 0; s >>= 1) ssum += __shfl_xor(ssum, s);
    float p = ev / ssum;

    float pv = p;
    int ids[TOPK]; float wsel[TOPK]; float wsum = 0.f;
    #pragma unroll
    for (int i = 0; i < TOPK; ++i) {
        float mx = pv;
        #pragma unroll
        for (int s = 32; s > 0; s >>= 1) mx = fmaxf(mx, __shfl_xor(mx, s));
        unsigned long long b = __ballot(pv == mx);
        int idx = (int)__builtin_ctzll(b);
        float w = __shfl(p, idx);
        ids[i] = idx; wsel[i] = w; wsum += w;
        if (lane == idx) pv = -1.0f;
    }
    if (lane < TOPK) {
        top_ids[t * TOPK + lane] = ids[lane];
        top_w[t * TOPK + lane]  = wsel[lane] / wsum;
    }
    if (lane == 0) {
        #pragma unroll
        for (int i = 0; i < TOPK; ++i)
            if ((ids[i] & 7) == 0) atomicAdd(&cnt[ids[i] >> 3], 1);
    }
}

__global__ void k_offsets(int* __restrict__ cnt, int* __restrict__ cnt2,
                          int* __restrict__ offs)
{
    if (threadIdx.x == 0) {
        int s = 0;
        for (int e = 0; e < NLOC; ++e) { offs[e] = s; s += cnt[e]; cnt2[e] = 0; }
    }
}

__global__ __launch_bounds__(256) void k_scatter(
    const int* __restrict__ top_ids, const float* __restrict__ top_w,
    const int* __restrict__ offs, int* __restrict__ cnt2,
    int* __restrict__ tok_of, float* __restrict__ w_of)
{
    const int t = blockIdx.x * 256 + threadIdx.x;
    #pragma unroll
    for (int i = 0; i < TOPK; ++i) {
        int id = top_ids[t * TOPK + i];
        if ((id & 7) == 0) {
            int e = id >> 3;
            int s = offs[e] + atomicAdd(&cnt2[e], 1);
            tok_of[s] = t;
            w_of[s]  = top_w[t * TOPK + i];
        }
    }
}

// ---------------- x fp32 -> bf16 once ----------------
__global__ __launch_bounds__(256) void k_cvt_x(const float* __restrict__ x,
                                               short* __restrict__ xbf)
{
    const int r = blockIdx.x;
    const int c = threadIdx.x * 8;
    const float4 a = *(const float4*)&x[(size_t)r * HID + c];
    const float4 b = *(const float4*)&x[(size_t)r * HID + c + 4];
    s16x8 v = { f2bf(a.x), f2bf(a.y), f2bf(a.z), f2bf(a.w),
                f2bf(b.x), f2bf(b.y), f2bf(b.z), f2bf(b.w) };
    *(s16x8*)&xbf[(size_t)r * HID + c] = v;
}

// ------------- GEMM1: M=256 (all tokens of expert) x N=32 pair-cols, K-step 64 -------------
__global__ __launch_bounds__(256, 2) void k_gemm1(
    const short* __restrict__ xbf, const float* __restrict__ w13,
    const float* __restrict__ w13s, const int* __restrict__ offs,
    const int* __restrict__ cnt, const int* __restrict__ tok_of,
    short* __restrict__ a_buf)
{
    const int e = blockIdx.z;
    const int cntE = cnt[e];
    const int m0 = blockIdx.y * 256;
    if (m0 >= cntE) return;
    const int n0p = blockIdx.x * 32;          // pair-col base in [0, ITR)
    const int base = offs[e] + m0;
    const int tid = threadIdx.x;
    const int lane = tid & 63;
    const int wm = tid >> 6;                  // wave id 0..3 -> owns rows wm*64..+63

    __shared__ __align__(16) short As[2][256 * 64];   // 64 KB
    __shared__ __align__(16) short Ws[2][64 * 64];    // 16 KB (32 gate + 32 up rows)

    // stage token ids through As[0] (reused before first WRITE)
    int* tokp = (int*)&As[0][0];
    tokp[tid] = tok_of[base + ((m0 + tid < cntE) ? tid : 0)];
    __syncthreads();

    const short* aptr[8];
    int aoff[8];
    #pragma unroll
    for (int p = 0; p < 8; ++p) {
        const int row = p * 32 + (tid >> 3), cg = tid & 7;
        aptr[p] = xbf + (size_t)tokp[row] * HID + cg * 8;
        aoff[p] = (row * 64 + cg * 8) ^ ((row & 7) << 3);
    }
    __syncthreads();   // done reading tokp; As[0] free for staging

    const float* wptr[4];
    int woff[4];
    {
        const float* wg = w13 + ((size_t)e * ITR2 + n0p) * HID;
        const float* wu = w13 + ((size_t)e * ITR2 + ITR + n0p) * HID;
        #pragma unroll
        for (int p = 0; p < 4; ++p) {
            const int row = p * 16 + (tid >> 4), ch = tid & 15;
            wptr[p] = ((p < 2) ? wg : wu) + (size_t)(row & 31) * HID + ch * 4;
            woff[p] = (row * 64 + ch * 4) ^ ((row & 7) << 3);
        }
    }
    const int sgi = (e * 22 + (n0p >> 7)) * 16;
    const int sui = (e * 22 + 11 + (n0p >> 7)) * 16;

    s16x8 ra[8];
    float4 rw[4];
    float sgv, suv;
    f32x4 acc[2][2][4] = {};    // [gate/up][nf][mf]

#define G1_LOAD(kk) do {                                                       \
    const int k0 = (kk) * 64;                                                  \
    sgv = w13s[sgi + ((kk) >> 1)];                                             \
    suv = w13s[sui + ((kk) >> 1)];                                             \
    _Pragma("unroll")                                                          \
    for (int p = 0; p < 8; ++p) ra[p] = *(const s16x8*)(aptr[p] + k0);         \
    _Pragma("unroll")                                                          \
    for (int p = 0; p < 4; ++p) rw[p] = *(const float4*)(wptr[p] + k0);        \
} while (0)

#define G1_WRITE(b) do {                                                       \
    _Pragma("unroll")                                                          \
    for (int p = 0; p < 8; ++p) *(s16x8*)&As[b][aoff[p]] = ra[p];              \
    _Pragma("unroll")                                                          \
    for (int p = 0; p < 4; ++p) {                                              \
        const float s = (p < 2) ? sgv : suv;                                   \
        s16x4 v = { f2bf(rw[p].x * s), f2bf(rw[p].y * s),                      \
                    f2bf(rw[p].z * s), f2bf(rw[p].w * s) };                    \
        *(s16x4*)&Ws[b][woff[p]] = v;                                          \
    }                                                                          \
} while (0)

#define G1_COMP(b) do {                                                        \
    _Pragma("unroll")                                                          \
    for (int ks = 0; ks < 2; ++ks) {                                           \
        const int co = ks * 32 + (lane >> 4) * 8;                              \
        s16x8 af[4];                                                           \
        _Pragma("unroll")                                                      \
        for (int mf = 0; mf < 4; ++mf) {                                       \
            const int row = wm * 64 + mf * 16 + (lane & 15);                   \
            af[mf] = *(const s16x8*)&As[b][(row * 64 + co) ^ ((row & 7) << 3)];\
        }                                                                      \
        _Pragma("unroll")                                                      \
        for (int t = 0; t < 2; ++t)                                            \
        _Pragma("unroll")                                                      \
        for (int nf = 0; nf < 2; ++nf) {                                       \
            const int row = t * 32 + nf * 16 + (lane & 15);                    \
            s16x8 bv = *(const s16x8*)&Ws[b][(row * 64 + co) ^ ((row & 7) << 3)];\
            _Pragma("unroll")                                                  \
            for (int mf = 0; mf < 4; ++mf)                                     \
                acc[t][nf][mf] = __builtin_amdgcn_mfma_f32_16x16x32_bf16(af[mf], bv, acc[t][nf][mf], 0, 0, 0); \
        }                                                                      \
    }                                                                          \
} while (0)

    G1_LOAD(0);
    G1_WRITE(0);
    __syncthreads();
    #pragma unroll 2
    for (int k = 0; k < NK1; ++k) {
        if (k + 1 < NK1) G1_LOAD(k + 1);
        G1_COMP(k & 1);
        if (k + 1 < NK1) {
            G1_WRITE((k & 1) ^ 1);
            __syncthreads();
        }
    }

    // epilogue: silu(gate)*up -> a_buf bf16
    #pragma unroll
    for (int nf = 0; nf < 2; ++nf) {
        const int col = n0p + nf * 16 + (lane & 15);
        #pragma unroll
        for (int mf = 0; mf < 4; ++mf)
        #pragma unroll
        for (int j = 0; j < 4; ++j) {
            const int row = wm * 64 + mf * 16 + (lane >> 4) * 4 + j;
            if (m0 + row < cntE) {
                const float g = acc[0][nf][mf][j], u = acc[1][nf][mf][j];
                const float a = (g / (1.f + __expf(-g))) * u;
                a_buf[(size_t)(base + row) * ITR + col] = f2bf(a);
            }
        }
    }
#undef G1_LOAD
#undef G1_WRITE
#undef G1_COMP
}

// ------------- GEMM2: M=256 x N=32 out-cols, K=1408 -------------
__global__ __launch_bounds__(256, 2) void k_gemm2(
    const short* __restrict__ a_buf, const float* __restrict__ w2,
    const float* __restrict__ w2s, const int* __restrict__ offs,
    const int* __restrict__ cnt, const int* __restrict__ tok_of,
    const float* __restrict__ w_of, float* __restrict__ out)
{
    const int e = blockIdx.z;
    const int cntE = cnt[e];
    const int m0 = blockIdx.y * 256;
    if (m0 >= cntE) return;
    const int n0 = blockIdx.x * 32;
    const int base = offs[e] + m0;
    const int tid = threadIdx.x;
    const int lane = tid & 63;
    const int wm = tid >> 6;

    __shared__ __align__(16) short As[2][256 * 64];   // 64 KB
    __shared__ __align__(16) short Ws[2][32 * 64];    // 8 KB

    const short* aptr[8];
    int aoff[8];
    #pragma unroll
    for (int p = 0; p < 8; ++p) {
        const int row = p * 32 + (tid >> 3), cg = tid & 7;
        int srow = base + row; if (srow > NSLOT - 1) srow = NSLOT - 1;
        aptr[p] = a_buf + (size_t)srow * ITR + cg * 8;
        aoff[p] = (row * 64 + cg * 8) ^ ((row & 7) << 3);
    }
    const float* wptr[2];
    int woff[2];
    #pragma unroll
    for (int p = 0; p < 2; ++p) {
        const int row = p * 16 + (tid >> 4), ch = tid & 15;
        wptr[p] = w2 + ((size_t)e * HID + n0 + row) * ITR + ch * 4;
        woff[p] = (row * 64 + ch * 4) ^ ((row & 7) << 3);
    }
    const int sci = (e * 16 + (n0 >> 7)) * 11;

    s16x8 ra[8];
    float4 rw[2];
    float scv;
    f32x4 acc[2][4] = {};    // [nf][mf]

#define G2_LOAD(kk) do {                                                       \
    const int k0 = (kk) * 64;                                                  \
    scv = w2s[sci + ((kk) >> 1)];                                              \
    _Pragma("unroll")                                                          \
    for (int p = 0; p < 8; ++p) ra[p] = *(const s16x8*)(aptr[p] + k0);         \
    _Pragma("unroll")                                                          \
    for (int p = 0; p < 2; ++p) rw[p] = *(const float4*)(wptr[p] + k0);        \
} while (0)

#define G2_WRITE(b) do {                                                       \
    _Pragma("unroll")                                                          \
    for (int p = 0; p < 8; ++p) *(s16x8*)&As[b][aoff[p]] = ra[p];              \
    _Pragma("unroll")                                                          \
    for (int p = 0; p < 2; ++p) {                                              \
        s16x4 v = { f2bf(rw[p].x * scv), f2bf(rw[p].y * scv),                  \
                    f2bf(rw[p].z * scv), f2bf(rw[p].w * scv) };                \
        *(s16x4*)&Ws[b][woff[p]] = v;                                          \
    }                                                                          \
} while (0)

#define G2_COMP(b) do {                                                        \
    _Pragma("unroll")                                                          \
    for (int ks = 0; ks < 2; ++ks) {                                           \
        const int co = ks * 32 + (lane >> 4) * 8;                              \
        s16x8 af[4];                                                           \
        _Pragma("unroll")                                                      \
        for (int mf = 0; mf < 4; ++mf) {                                       \
            const int row = wm * 64 + mf * 16 + (lane & 15);                   \
            af[mf] = *(const s16x8*)&As[b][(row * 64 + co) ^ ((row & 7) << 3)];\
        }                                                                      \
        _Pragma("unroll")                                                      \
        for (int nf = 0; nf < 2; ++nf) {                                       \
            const int row = nf * 16 + (lane & 15);                             \
            s16x8 bv = *(const s16x8*)&Ws[b][(row * 64 + co) ^ ((row & 7) << 3)];\
            _Pragma("unroll")                                                  \
            for (int mf = 0; mf < 4; ++mf)                                     \
                acc[nf][mf] = __builtin_amdgcn_mfma_f32_16x16x32_bf16(af[mf], bv, acc[nf][mf], 0, 0, 0); \
        }                                                                      \
    }                                                                          \
} while (0)

    G2_LOAD(0);
    G2_WRITE(0);
    __syncthreads();
    #pragma unroll 2
    for (int k = 0; k < NK2; ++k) {
        if (k + 1 < NK2) G2_LOAD(k + 1);
        G2_COMP(k & 1);
        if (k + 1 < NK2) {
            G2_WRITE((k & 1) ^ 1);
            __syncthreads();
        }
    }

    #pragma unroll
    for (int mf = 0; mf < 4; ++mf)
    #pragma unroll
    for (int j = 0; j < 4; ++j) {
        const int row = wm * 64 + mf * 16 + (lane >> 4) * 4 + j;
        if (m0 + row < cntE) {
            const int   t = tok_of[base + row];
            const float w = w_of[base + row];
            #pragma unroll
            for (int nf = 0; nf < 2; ++nf) {
                const int col = n0 + nf * 16 + (lane & 15);
                atomicAdd(&out[(size_t)t * HID + col], acc[nf][mf][j] * w);
            }
        }
    }
#undef G2_LOAD
#undef G2_WRITE
#undef G2_COMP
}

extern "C" void kernel_launch(void* const* d_in, const int* in_sizes, int n_in,
                              void* d_out, int out_size, void* d_ws, size_t ws_size,
                              hipStream_t stream)
{
    const float* x      = (const float*)d_in[0];
    const float* logits = (const float*)d_in[1];
    const float* w13    = (const float*)d_in[2];
    const float* w13s   = (const float*)d_in[3];
    const float* w2     = (const float*)d_in[4];
    const float* w2s    = (const float*)d_in[5];
    float* out = (float*)d_out;
    char*  ws  = (char*)d_ws;

    int*   cnt     = (int*)(ws + OFF_CNT);
    int*   cnt2    = (int*)(ws + OFF_CNT2);
    int*   offs    = (int*)(ws + OFF_OFFS);
    int*   top_ids = (int*)(ws + OFF_TOPID);
    float* top_w   = (float*)(ws + OFF_TOPW);
    int*   tok_of  = (int*)(ws + OFF_TOK);
    float* w_of    = (float*)(ws + OFF_WOF);
    short* xbf     = (short*)(ws + OFF_XBF);
    short* a_buf   = (short*)(ws + OFF_ABUF);

    k_zero   <<<1024,        256, 0, stream>>>(out, cnt);   // d_out (16.8 MB) + cnt/cnt2
    k_route  <<<T_TOK / 4,   256, 0, stream>>>(logits, cnt, top_ids, top_w);
    k_offsets<<<1,            64, 0, stream>>>(cnt, cnt2, offs);
    k_scatter<<<T_TOK / 256, 256, 0, stream>>>(top_ids, top_w, offs, cnt2, tok_of, w_of);
    k_cvt_x  <<<T_TOK,       256, 0, stream>>>(x, xbf);
    k_gemm1  <<<dim3(44, 8, NLOC), 256, 0, stream>>>(xbf, w13, w13s, offs, cnt, tok_of, a_buf);
    k_gemm2  <<<dim3(64, 8, NLOC), 256, 0, stream>>>(a_buf, w2, w2s, offs, cnt, tok_of, w_of, out);
}

// Round 5
// 168.262 us; speedup vs baseline: 5.6964x; 1.0067x over previous
//
#include <hip/hip_runtime.h>
#include <hip/hip_bf16.h>
#include <cstdint>

#define T_TOK 2048
#define HID   2048
#define NEXP  64
#define TOPK  6
#define NLOC  8
#define ITR   1408
#define ITR2  2816
#define NSLOT (T_TOK * TOPK)
#define NK1   32   // HID/64
#define NK2   22   // ITR/64

// workspace layout (bytes)
#define OFF_CNT   0
#define OFF_CNT2  32
#define OFF_OFFS  64
#define OFF_TOPID 4096
#define OFF_TOPW  (OFF_TOPID + T_TOK * TOPK * 4)
#define OFF_TOK   (OFF_TOPW  + T_TOK * TOPK * 4)
#define OFF_WOF   (OFF_TOK   + NSLOT * 4)
#define OFF_XBF   (OFF_WOF   + NSLOT * 4)
#define OFF_ABUF  (OFF_XBF   + (size_t)T_TOK * HID * 2)

typedef __attribute__((ext_vector_type(4))) float f32x4;
typedef __attribute__((ext_vector_type(8))) short s16x8;
typedef __attribute__((ext_vector_type(4))) short s16x4;

__device__ __forceinline__ short f2bf(float f) {
    union { float f; unsigned u; } v; v.f = f;
    unsigned r = v.u + 0x7FFFu + ((v.u >> 16) & 1u);
    return (short)(r >> 16);
}

// ---------------- zero d_out + routing counters ----------------
__global__ __launch_bounds__(256) void k_zero(float* __restrict__ out,
                                              int* __restrict__ cnt)
{
    const int idx = blockIdx.x * 256 + threadIdx.x;   // 262144 threads
    float4 z = {0.f, 0.f, 0.f, 0.f};
    #pragma unroll
    for (int p = 0; p < 4; ++p)
        *(float4*)&out[(size_t)(idx + p * 262144) * 4] = z;
    if (blockIdx.x == 0 && threadIdx.x < 16) cnt[threadIdx.x] = 0;
}

// ---------------- routing: softmax + top-6 (stable tie-break) ----------------
__global__ __launch_bounds__(256) void k_route(
    const float* __restrict__ logits, int* __restrict__ cnt,
    int* __restrict__ top_ids, float* __restrict__ top_w)
{
    const int lane = threadIdx.x & 63;
    const int t = blockIdx.x * 4 + (threadIdx.x >> 6);

    float v = logits[t * NEXP + lane];
    float m = v;
    #pragma unroll
    for (int s = 32; s > 0; s >>= 1) m = fmaxf(m, __shfl_xor(m, s));
    float ev = expf(v - m);
    float ssum = ev;
    #pragma unroll
    for (int s = 32; s > 0; s >>= 1) ssum += __shfl_xor(ssum, s);
    float p = ev / ssum;

    float pv = p;
    int ids[TOPK]; float wsel[TOPK]; float wsum = 0.f;
    #pragma unroll
    for (int i = 0; i < TOPK; ++i) {
        float mx = pv;
        #pragma unroll
        for (int s = 32; s > 0; s >>= 1) mx = fmaxf(mx, __shfl_xor(mx, s));
        unsigned long long b = __ballot(pv == mx);
        int idx = (int)__builtin_ctzll(b);
        float w = __shfl(p, idx);
        ids[i] = idx; wsel[i] = w; wsum += w;
        if (lane == idx) pv = -1.0f;
    }
    if (lane < TOPK) {
        top_ids[t * TOPK + lane] = ids[lane];
        top_w[t * TOPK + lane]  = wsel[lane] / wsum;
    }
    if (lane == 0) {
        #pragma unroll
        for (int i = 0; i < TOPK; ++i)
            if ((ids[i] & 7) == 0) atomicAdd(&cnt[ids[i] >> 3], 1);
    }
}

__global__ void k_offsets(int* __restrict__ cnt, int* __restrict__ cnt2,
                          int* __restrict__ offs)
{
    if (threadIdx.x == 0) {
        int s = 0;
        for (int e = 0; e < NLOC; ++e) { offs[e] = s; s += cnt[e]; cnt2[e] = 0; }
    }
}

__global__ __launch_bounds__(256) void k_scatter(
    const int* __restrict__ top_ids, const float* __restrict__ top_w,
    const int* __restrict__ offs, int* __restrict__ cnt2,
    int* __restrict__ tok_of, float* __restrict__ w_of)
{
    const int t = blockIdx.x * 256 + threadIdx.x;
    #pragma unroll
    for (int i = 0; i < TOPK; ++i) {
        int id = top_ids[t * TOPK + i];
        if ((id & 7) == 0) {
            int e = id >> 3;
            int s = offs[e] + atomicAdd(&cnt2[e], 1);
            tok_of[s] = t;
            w_of[s]  = top_w[t * TOPK + i];
        }
    }
}

// ---------------- x fp32 -> bf16 once ----------------
__global__ __launch_bounds__(256) void k_cvt_x(const float* __restrict__ x,
                                               short* __restrict__ xbf)
{
    const int r = blockIdx.x;
    const int c = threadIdx.x * 8;
    const float4 a = *(const float4*)&x[(size_t)r * HID + c];
    const float4 b = *(const float4*)&x[(size_t)r * HID + c + 4];
    s16x8 v = { f2bf(a.x), f2bf(a.y), f2bf(a.z), f2bf(a.w),
                f2bf(b.x), f2bf(b.y), f2bf(b.z), f2bf(b.w) };
    *(s16x8*)&xbf[(size_t)r * HID + c] = v;
}

// ------------- GEMM1: M=256 (all tokens of expert) x N=32 pair-cols, K-step 64 -------------
// flat grid, expert in low 3 bits => all blocks of expert e land on XCD e (round-robin)
__global__ __launch_bounds__(256, 2) void k_gemm1(
    const short* __restrict__ xbf, const float* __restrict__ w13,
    const float* __restrict__ w13s, const int* __restrict__ offs,
    const int* __restrict__ cnt, const int* __restrict__ tok_of,
    short* __restrict__ a_buf)
{
    const int b = blockIdx.x;
    const int e = b & 7;
    const int tt = b >> 3;
    const int cntE = cnt[e];
    const int m0 = (tt / 44) * 256;
    if (m0 >= cntE) return;
    const int n0p = (tt % 44) * 32;           // pair-col base in [0, ITR)
    const int base = offs[e] + m0;
    const int tid = threadIdx.x;
    const int lane = tid & 63;
    const int wm = tid >> 6;                  // wave id 0..3 -> owns rows wm*64..+63

    __shared__ __align__(16) short As[2][256 * 64];   // 64 KB
    __shared__ __align__(16) short Ws[2][64 * 64];    // 16 KB (32 gate + 32 up rows)

    // stage token ids through As[0] (reused before first WRITE)
    int* tokp = (int*)&As[0][0];
    tokp[tid] = tok_of[base + ((m0 + tid < cntE) ? tid : 0)];
    __syncthreads();

    const short* aptr[8];
    int aoff[8];
    #pragma unroll
    for (int p = 0; p < 8; ++p) {
        const int row = p * 32 + (tid >> 3), cg = tid & 7;
        aptr[p] = xbf + (size_t)tokp[row] * HID + cg * 8;
        aoff[p] = (row * 64 + cg * 8) ^ ((row & 7) << 3);
    }
    __syncthreads();   // done reading tokp; As[0] free for staging

    const float* wptr[4];
    int woff[4];
    {
        const float* wg = w13 + ((size_t)e * ITR2 + n0p) * HID;
        const float* wu = w13 + ((size_t)e * ITR2 + ITR + n0p) * HID;
        #pragma unroll
        for (int p = 0; p < 4; ++p) {
            const int row = p * 16 + (tid >> 4), ch = tid & 15;
            wptr[p] = ((p < 2) ? wg : wu) + (size_t)(row & 31) * HID + ch * 4;
            woff[p] = (row * 64 + ch * 4) ^ ((row & 7) << 3);
        }
    }
    const int sgi = (e * 22 + (n0p >> 7)) * 16;
    const int sui = (e * 22 + 11 + (n0p >> 7)) * 16;

    s16x8 ra[8];
    float4 rw[4];
    float sgv, suv;
    f32x4 acc[2][2][4] = {};    // [gate/up][nf][mf]

#define G1_LOAD(kk) do {                                                       \
    const int k0 = (kk) * 64;                                                  \
    sgv = w13s[sgi + ((kk) >> 1)];                                             \
    suv = w13s[sui + ((kk) >> 1)];                                             \
    _Pragma("unroll")                                                          \
    for (int p = 0; p < 8; ++p) ra[p] = *(const s16x8*)(aptr[p] + k0);         \
    _Pragma("unroll")                                                          \
    for (int p = 0; p < 4; ++p) rw[p] = *(const float4*)(wptr[p] + k0);        \
} while (0)

#define G1_WRITE(b) do {                                                       \
    _Pragma("unroll")                                                          \
    for (int p = 0; p < 8; ++p) *(s16x8*)&As[b][aoff[p]] = ra[p];              \
    _Pragma("unroll")                                                          \
    for (int p = 0; p < 4; ++p) {                                              \
        const float s = (p < 2) ? sgv : suv;                                   \
        s16x4 v = { f2bf(rw[p].x * s), f2bf(rw[p].y * s),                      \
                    f2bf(rw[p].z * s), f2bf(rw[p].w * s) };                    \
        *(s16x4*)&Ws[b][woff[p]] = v;                                          \
    }                                                                          \
} while (0)

#define G1_COMP(b) do {                                                        \
    _Pragma("unroll")                                                          \
    for (int ks = 0; ks < 2; ++ks) {                                           \
        const int co = ks * 32 + (lane >> 4) * 8;                              \
        s16x8 af[4];                                                           \
        _Pragma("unroll")                                                      \
        for (int mf = 0; mf < 4; ++mf) {                                       \
            const int row = wm * 64 + mf * 16 + (lane & 15);                   \
            af[mf] = *(const s16x8*)&As[b][(row * 64 + co) ^ ((row & 7) << 3)];\
        }                                                                      \
        _Pragma("unroll")                                                      \
        for (int t = 0; t < 2; ++t)                                            \
        _Pragma("unroll")                                                      \
        for (int nf = 0; nf < 2; ++nf) {                                       \
            const int row = t * 32 + nf * 16 + (lane & 15);                    \
            s16x8 bv = *(const s16x8*)&Ws[b][(row * 64 + co) ^ ((row & 7) << 3)];\
            _Pragma("unroll")                                                  \
            for (int mf = 0; mf < 4; ++mf)                                     \
                acc[t][nf][mf] = __builtin_amdgcn_mfma_f32_16x16x32_bf16(af[mf], bv, acc[t][nf][mf], 0, 0, 0); \
        }                                                                      \
    }                                                                          \
} while (0)

    G1_LOAD(0);
    G1_WRITE(0);
    __syncthreads();
    #pragma unroll 2
    for (int k = 0; k < NK1; ++k) {
        if (k + 1 < NK1) G1_LOAD(k + 1);
        G1_COMP(k & 1);
        if (k + 1 < NK1) {
            G1_WRITE((k & 1) ^ 1);
            __syncthreads();
        }
    }

    // epilogue: silu(gate)*up -> a_buf bf16
    #pragma unroll
    for (int nf = 0; nf < 2; ++nf) {
        const int col = n0p + nf * 16 + (lane & 15);
        #pragma unroll
        for (int mf = 0; mf < 4; ++mf)
        #pragma unroll
        for (int j = 0; j < 4; ++j) {
            const int row = wm * 64 + mf * 16 + (lane >> 4) * 4 + j;
            if (m0 + row < cntE) {
                const float g = acc[0][nf][mf][j], u = acc[1][nf][mf][j];
                const float a = (g / (1.f + __expf(-g))) * u;
                a_buf[(size_t)(base + row) * ITR + col] = f2bf(a);
            }
        }
    }
#undef G1_LOAD
#undef G1_WRITE
#undef G1_COMP
}

// ------------- GEMM2: M=256 x N=32 out-cols, K=1408 -------------
__global__ __launch_bounds__(256, 2) void k_gemm2(
    const short* __restrict__ a_buf, const float* __restrict__ w2,
    const float* __restrict__ w2s, const int* __restrict__ offs,
    const int* __restrict__ cnt, const int* __restrict__ tok_of,
    const float* __restrict__ w_of, float* __restrict__ out)
{
    const int b = blockIdx.x;
    const int e = b & 7;
    const int tt = b >> 3;
    const int cntE = cnt[e];
    const int m0 = (tt / 64) * 256;
    if (m0 >= cntE) return;
    const int n0 = (tt % 64) * 32;
    const int base = offs[e] + m0;
    const int tid = threadIdx.x;
    const int lane = tid & 63;
    const int wm = tid >> 6;

    __shared__ __align__(16) short As[2][256 * 64];   // 64 KB
    __shared__ __align__(16) short Ws[2][32 * 64];    // 8 KB

    const short* aptr[8];
    int aoff[8];
    #pragma unroll
    for (int p = 0; p < 8; ++p) {
        const int row = p * 32 + (tid >> 3), cg = tid & 7;
        int srow = base + row; if (srow > NSLOT - 1) srow = NSLOT - 1;
        aptr[p] = a_buf + (size_t)srow * ITR + cg * 8;
        aoff[p] = (row * 64 + cg * 8) ^ ((row & 7) << 3);
    }
    const float* wptr[2];
    int woff[2];
    #pragma unroll
    for (int p = 0; p < 2; ++p) {
        const int row = p * 16 + (tid >> 4), ch = tid & 15;
        wptr[p] = w2 + ((size_t)e * HID + n0 + row) * ITR + ch * 4;
        woff[p] = (row * 64 + ch * 4) ^ ((row & 7) << 3);
    }
    const int sci = (e * 16 + (n0 >> 7)) * 11;

    s16x8 ra[8];
    float4 rw[2];
    float scv;
    f32x4 acc[2][4] = {};    // [nf][mf]

#define G2_LOAD(kk) do {                                                       \
    const int k0 = (kk) * 64;                                                  \
    scv = w2s[sci + ((kk) >> 1)];                                              \
    _Pragma("unroll")                                                          \
    for (int p = 0; p < 8; ++p) ra[p] = *(const s16x8*)(aptr[p] + k0);         \
    _Pragma("unroll")                                                          \
    for (int p = 0; p < 2; ++p) rw[p] = *(const float4*)(wptr[p] + k0);        \
} while (0)

#define G2_WRITE(b) do {                                                       \
    _Pragma("unroll")                                                          \
    for (int p = 0; p < 8; ++p) *(s16x8*)&As[b][aoff[p]] = ra[p];              \
    _Pragma("unroll")                                                          \
    for (int p = 0; p < 2; ++p) {                                              \
        s16x4 v = { f2bf(rw[p].x * scv), f2bf(rw[p].y * scv),                  \
                    f2bf(rw[p].z * scv), f2bf(rw[p].w * scv) };                \
        *(s16x4*)&Ws[b][woff[p]] = v;                                          \
    }                                                                          \
} while (0)

#define G2_COMP(b) do {                                                        \
    _Pragma("unroll")                                                          \
    for (int ks = 0; ks < 2; ++ks) {                                           \
        const int co = ks * 32 + (lane >> 4) * 8;                              \
        s16x8 af[4];                                                           \
        _Pragma("unroll")                                                      \
        for (int mf = 0; mf < 4; ++mf) {                                       \
            const int row = wm * 64 + mf * 16 + (lane & 15);                   \
            af[mf] = *(const s16x8*)&As[b][(row * 64 + co) ^ ((row & 7) << 3)];\
        }                                                                      \
        _Pragma("unroll")                                                      \
        for (int nf = 0; nf < 2; ++nf) {                                       \
            const int row = nf * 16 + (lane & 15);                             \
            s16x8 bv = *(const s16x8*)&Ws[b][(row * 64 + co) ^ ((row & 7) << 3)];\
            _Pragma("unroll")                                                  \
            for (int mf = 0; mf < 4; ++mf)                                     \
                acc[nf][mf] = __builtin_amdgcn_mfma_f32_16x16x32_bf16(af[mf], bv, acc[nf][mf], 0, 0, 0); \
        }                                                                      \
    }                                                                          \
} while (0)

    G2_LOAD(0);
    G2_WRITE(0);
    __syncthreads();
    #pragma unroll 2
    for (int k = 0; k < NK2; ++k) {
        if (k + 1 < NK2) G2_LOAD(k + 1);
        G2_COMP(k & 1);
        if (k + 1 < NK2) {
            G2_WRITE((k & 1) ^ 1);
            __syncthreads();
        }
    }

    #pragma unroll
    for (int mf = 0; mf < 4; ++mf)
    #pragma unroll
    for (int j = 0; j < 4; ++j) {
        const int row = wm * 64 + mf * 16 + (lane >> 4) * 4 + j;
        if (m0 + row < cntE) {
            const int   t = tok_of[base + row];
            const float w = w_of[base + row];
            #pragma unroll
            for (int nf = 0; nf < 2; ++nf) {
                const int col = n0 + nf * 16 + (lane & 15);
                atomicAdd(&out[(size_t)t * HID + col], acc[nf][mf][j] * w);
            }
        }
    }
#undef G2_LOAD
#undef G2_WRITE
#undef G2_COMP
}

extern "C" void kernel_launch(void* const* d_in, const int* in_sizes, int n_in,
                              void* d_out, int out_size, void* d_ws, size_t ws_size,
                              hipStream_t stream)
{
    const float* x      = (const float*)d_in[0];
    const float* logits = (const float*)d_in[1];
    const float* w13    = (const float*)d_in[2];
    const float* w13s   = (const float*)d_in[3];
    const float* w2     = (const float*)d_in[4];
    const float* w2s    = (const float*)d_in[5];
    float* out = (float*)d_out;
    char*  ws  = (char*)d_ws;

    int*   cnt     = (int*)(ws + OFF_CNT);
    int*   cnt2    = (int*)(ws + OFF_CNT2);
    int*   offs    = (int*)(ws + OFF_OFFS);
    int*   top_ids = (int*)(ws + OFF_TOPID);
    float* top_w   = (float*)(ws + OFF_TOPW);
    int*   tok_of  = (int*)(ws + OFF_TOK);
    float* w_of    = (float*)(ws + OFF_WOF);
    short* xbf     = (short*)(ws + OFF_XBF);
    short* a_buf   = (short*)(ws + OFF_ABUF);

    k_zero   <<<1024,        256, 0, stream>>>(out, cnt);   // d_out (16.8 MB) + cnt/cnt2
    k_route  <<<T_TOK / 4,   256, 0, stream>>>(logits, cnt, top_ids, top_w);
    k_offsets<<<1,            64, 0, stream>>>(cnt, cnt2, offs);
    k_scatter<<<T_TOK / 256, 256, 0, stream>>>(top_ids, top_w, offs, cnt2, tok_of, w_of);
    k_cvt_x  <<<T_TOK,       256, 0, stream>>>(x, xbf);
    k_gemm1  <<<44 * 8 * NLOC, 256, 0, stream>>>(xbf, w13, w13s, offs, cnt, tok_of, a_buf);
    k_gemm2  <<<64 * 8 * NLOC, 256, 0, stream>>>(a_buf, w2, w2s, offs, cnt, tok_of, w_of, out);
}